// Round 2
// baseline (32.088 us; speedup 1.0000x reference)
//
#include <hip/hip_runtime.h>
#include <cfloat>
#include <climits>

#define TT 1024
#define BB 16
#define DD 512
#define VV 1000

// Kernel 1: one 64-lane wave per (t,b) position computes argmax over V logits.
// 1024-thread blocks (16 rows each) to cut dispatch count to 1024.
__global__ void argmax_kernel(const float* __restrict__ logit, int* __restrict__ labels) {
    int gw   = (blockIdx.x * blockDim.x + threadIdx.x) >> 6;   // global wave id = t*B + b
    int lane = threadIdx.x & 63;
    const float4* row = (const float4*)(logit + (size_t)gw * VV);  // 4000B rows, 16B aligned
    float best = -FLT_MAX;
    int   bidx = INT_MAX;
    for (int i = lane; i < VV / 4; i += 64) {           // 250 float4 per row
        float4 v = row[i];
        int base = i * 4;
        // within-lane indices ascend, so strict > keeps the earliest index
        if (v.x > best) { best = v.x; bidx = base;     }
        if (v.y > best) { best = v.y; bidx = base + 1; }
        if (v.z > best) { best = v.z; bidx = base + 2; }
        if (v.w > best) { best = v.w; bidx = base + 3; }
    }
    // cross-lane reduce with index tie-break (lower index wins on equal value)
    for (int off = 32; off; off >>= 1) {
        float ov = __shfl_xor(best, off);
        int   oi = __shfl_xor(bidx, off);
        if (ov > best || (ov == best && oi < bidx)) { best = ov; bidx = oi; }
    }
    if (lane == 0) {
        int t = gw / BB, b = gw % BB;                   // logit layout is (T,B,V)
        labels[b * TT + t] = bidx;                      // store as (B,T)
    }
}

// Kernel 2: one 1024-thread block per batch. Inclusive scan of change flags ->
// seg ids; LDS atomic counts -> per-timestep weight 1/runlen; seg starts; padding.
__global__ void seg_kernel(const int* __restrict__ labels,
                           const unsigned char* __restrict__ padding,
                           float* __restrict__ w, int* __restrict__ seg_start,
                           int* __restrict__ nseg, float* __restrict__ out_pad) {
    int b = blockIdx.x;
    int t = threadIdx.x;                 // 0..1023
    int lane = t & 63, wid = t >> 6;
    __shared__ int wsum[16];
    __shared__ int cnt[TT];

    int lab   = labels[b * TT + t];
    int prev  = (t > 0) ? labels[b * TT + t - 1] : -1;   // shifted label, -1 at t=0
    int valid = padding[b * TT + t] ? 0 : 1;
    int change = (valid && lab != prev) ? 1 : 0;

    // wave-level inclusive scan
    int x = change;
    for (int off = 1; off < 64; off <<= 1) {
        int y = __shfl_up(x, off);
        if (lane >= off) x += y;
    }
    if (lane == 63) wsum[wid] = x;
    cnt[t] = 0;
    __syncthreads();
    if (t == 0) {                         // serial scan of 16 wave totals
        int acc = 0;
        for (int i = 0; i < 16; ++i) { acc += wsum[i]; wsum[i] = acc; }
    }
    __syncthreads();
    int incl = x + (wid > 0 ? wsum[wid - 1] : 0);  // cumsum(change)[t]
    int seg  = incl - 1;                            // seg_id per reference
    int ns   = wsum[15];                            // total segments this batch

    if (valid && seg >= 0) atomicAdd(&cnt[seg], 1);
    if (change) seg_start[b * TT + seg] = t;
    __syncthreads();

    w[b * TT + t] = (valid && seg >= 0) ? (1.0f / (float)cnt[seg]) : 0.0f;
    out_pad[b * TT + t] = (t >= ns) ? 1.0f : 0.0f;  // new_padding as 0/1 floats
    if (t == 0) nseg[b] = ns;
}

// Kernel 3: 256-thread block handles 8 consecutive output rows (o = s*B+b):
// 2 rows in parallel (128 threads each, one float4 of D=512 per thread),
// 4 sequential iterations. 2048 blocks total, 16KB contiguous write per block.
#define ROWS_PER_BLOCK 8
__global__ void compress_kernel(const float* __restrict__ rep,
                                const float* __restrict__ w,
                                const int* __restrict__ seg_start,
                                const int* __restrict__ nseg,
                                float* __restrict__ out) {
    int tid = threadIdx.x;                // 0..255
    int sub = tid >> 7;                   // 0..1: row slot
    int dq  = tid & 127;                  // float4 index within D
    int base = blockIdx.x * ROWS_PER_BLOCK;
    for (int r = sub; r < ROWS_PER_BLOCK; r += 2) {
        int o = base + r;                 // o = s*BB + b
        int b = o & (BB - 1);
        int s = o >> 4;
        int ns = nseg[b];
        float4 acc = make_float4(0.f, 0.f, 0.f, 0.f);
        if (s < ns) {
            int start = seg_start[b * TT + s];
            int end   = (s + 1 < ns) ? seg_start[b * TT + s + 1] : TT;
            for (int t = start; t < end; ++t) {
                float ww = w[b * TT + t];     // broadcast read
                if (ww != 0.0f) {             // skips invalid (padded) timesteps
                    float4 rv = ((const float4*)rep)[((size_t)t * BB + b) * (DD / 4) + dq];
                    acc.x += ww * rv.x; acc.y += ww * rv.y;
                    acc.z += ww * rv.z; acc.w += ww * rv.w;
                }
            }
        }
        ((float4*)out)[(size_t)o * (DD / 4) + dq] = acc;  // zeros past ns
    }
}

extern "C" void kernel_launch(void* const* d_in, const int* in_sizes, int n_in,
                              void* d_out, int out_size, void* d_ws, size_t ws_size,
                              hipStream_t stream) {
    const float* rep            = (const float*)d_in[0];
    const float* logit          = (const float*)d_in[1];
    const unsigned char* paddng = (const unsigned char*)d_in[2];

    float* out     = (float*)d_out;
    float* out_pad = out + (size_t)TT * BB * DD;     // second output: (B,T) mask

    char* ws       = (char*)d_ws;
    int*   labels    = (int*)(ws);                   // B*T int   = 64 KiB
    float* w         = (float*)(ws + (1 << 16));     // B*T float = 64 KiB
    int*   seg_start = (int*)(ws + (2 << 16));       // B*T int   = 64 KiB
    int*   nseg      = (int*)(ws + (3 << 16));       // B int

    argmax_kernel  <<<(TT * BB) / 16, 1024, 0, stream>>>(logit, labels);
    seg_kernel     <<<BB, TT, 0, stream>>>(labels, paddng, w, seg_start, nseg, out_pad);
    compress_kernel<<<(TT * BB) / ROWS_PER_BLOCK, 256, 0, stream>>>(rep, w, seg_start, nseg, out);
}

// Round 3
// 29.863 us; speedup vs baseline: 1.0745x; 1.0745x over previous
//
#include <hip/hip_runtime.h>
#include <cfloat>
#include <climits>

#define TT 1024
#define BB 16
#define DD 512
#define VV 1000
#define CHUNK 8          // output rows (s values) per fused block
#define NCHUNK (TT / CHUNK)

// Kernel 1: one 64-lane wave per (t,b) position computes argmax over V logits.
__global__ void argmax_kernel(const float* __restrict__ logit, int* __restrict__ labels) {
    int gw   = (blockIdx.x * blockDim.x + threadIdx.x) >> 6;   // global wave id = t*B + b
    int lane = threadIdx.x & 63;
    const float4* row = (const float4*)(logit + (size_t)gw * VV);  // 4000B rows, 16B aligned
    float best = -FLT_MAX;
    int   bidx = INT_MAX;
    for (int i = lane; i < VV / 4; i += 64) {           // 250 float4 per row
        float4 v = row[i];
        int base = i * 4;
        if (v.x > best) { best = v.x; bidx = base;     }
        if (v.y > best) { best = v.y; bidx = base + 1; }
        if (v.z > best) { best = v.z; bidx = base + 2; }
        if (v.w > best) { best = v.w; bidx = base + 3; }
    }
    for (int off = 32; off; off >>= 1) {                // first-index tie-break
        float ov = __shfl_xor(best, off);
        int   oi = __shfl_xor(bidx, off);
        if (ov > best || (ov == best && oi < bidx)) { best = ov; bidx = oi; }
    }
    if (lane == 0) {
        int t = gw / BB, b = gw % BB;                   // logit layout is (T,B,V)
        labels[b * TT + t] = bidx;                      // store as (B,T)
    }
}

// Kernel 2: fused segmentation + compression. Block = (batch b, chunk of 8 s).
// Each block redundantly scans batch b's 1024 labels (4KB, L2-hit) into LDS
// seg structures, then gathers its 8 output rows. 256 threads, 4 t's/thread.
__global__ void __launch_bounds__(256) fused_compress_kernel(
        const int* __restrict__ labels,
        const unsigned char* __restrict__ padding,
        const float* __restrict__ rep,
        float* __restrict__ out, float* __restrict__ out_pad) {
    int b = blockIdx.x / NCHUNK;
    int c = blockIdx.x % NCHUNK;
    int tid = threadIdx.x;               // 0..255
    int lane = tid & 63, wid = tid >> 6; // 4 waves
    int t0 = tid * 4;

    __shared__ int   wtot[4];
    __shared__ int   cnt_s[TT];
    __shared__ int   start_s[TT];
    __shared__ float w_s[TT];

    // --- change flags for 4 consecutive t ---
    int4 lab4 = *(const int4*)(labels + b * TT + t0);
    int prev  = (t0 > 0) ? labels[b * TT + t0 - 1] : -1;   // raw previous label
    uchar4 p4 = *(const uchar4*)(padding + b * TT + t0);
    int v0 = !p4.x, v1 = !p4.y, v2 = !p4.z, v3 = !p4.w;
    int c0 = v0 && (lab4.x != prev);
    int c1 = v1 && (lab4.y != lab4.x);
    int c2 = v2 && (lab4.z != lab4.y);
    int c3 = v3 && (lab4.w != lab4.z);
    int l0 = c0, l1 = l0 + c1, l2 = l1 + c2, l3 = l2 + c3;  // local inclusive

    // --- wave inclusive scan of per-thread totals ---
    int x = l3;
    for (int off = 1; off < 64; off <<= 1) {
        int y = __shfl_up(x, off);
        if (lane >= off) x += y;
    }
    if (lane == 63) wtot[wid] = x;
    cnt_s[t0] = 0; cnt_s[t0 + 1] = 0; cnt_s[t0 + 2] = 0; cnt_s[t0 + 3] = 0;
    __syncthreads();
    int woff = 0;
    #pragma unroll
    for (int i = 0; i < 4; ++i) if (i < wid) woff += wtot[i];
    int ns   = wtot[0] + wtot[1] + wtot[2] + wtot[3];  // segments in batch b
    int excl = woff + x - l3;                          // exclusive prefix for t0

    int s0 = excl + l0 - 1, s1 = excl + l1 - 1, s2 = excl + l2 - 1, s3 = excl + l3 - 1;
    if (c0) start_s[s0] = t0;
    if (c1) start_s[s1] = t0 + 1;
    if (c2) start_s[s2] = t0 + 2;
    if (c3) start_s[s3] = t0 + 3;
    if (v0 && s0 >= 0) atomicAdd(&cnt_s[s0], 1);
    if (v1 && s1 >= 0) atomicAdd(&cnt_s[s1], 1);
    if (v2 && s2 >= 0) atomicAdd(&cnt_s[s2], 1);
    if (v3 && s3 >= 0) atomicAdd(&cnt_s[s3], 1);
    __syncthreads();
    w_s[t0]     = (v0 && s0 >= 0) ? (1.0f / (float)cnt_s[s0]) : 0.0f;
    w_s[t0 + 1] = (v1 && s1 >= 0) ? (1.0f / (float)cnt_s[s1]) : 0.0f;
    w_s[t0 + 2] = (v2 && s2 >= 0) ? (1.0f / (float)cnt_s[s2]) : 0.0f;
    w_s[t0 + 3] = (v3 && s3 >= 0) ? (1.0f / (float)cnt_s[s3]) : 0.0f;

    if (c == 0) {   // one chunk per batch emits the new padding mask
        float4 pm;
        pm.x = (t0     >= ns) ? 1.0f : 0.0f;
        pm.y = (t0 + 1 >= ns) ? 1.0f : 0.0f;
        pm.z = (t0 + 2 >= ns) ? 1.0f : 0.0f;
        pm.w = (t0 + 3 >= ns) ? 1.0f : 0.0f;
        *(float4*)(out_pad + b * TT + t0) = pm;
    }
    __syncthreads();

    // --- compress 8 rows: 2 in parallel (128 threads each), 4 iterations ---
    int sub = tid >> 7;                   // row slot 0/1
    int dq  = tid & 127;                  // float4 index within D=512
    #pragma unroll
    for (int r = sub; r < CHUNK; r += 2) {
        int s = c * CHUNK + r;
        float4 acc = make_float4(0.f, 0.f, 0.f, 0.f);
        if (s < ns) {
            int start = start_s[s];
            int end   = (s + 1 < ns) ? start_s[s + 1] : TT;
            for (int t = start; t < end; ++t) {
                float ww = w_s[t];
                if (ww != 0.0f) {
                    float4 rv = ((const float4*)rep)[((size_t)t * BB + b) * (DD / 4) + dq];
                    acc.x += ww * rv.x; acc.y += ww * rv.y;
                    acc.z += ww * rv.z; acc.w += ww * rv.w;
                }
            }
        }
        ((float4*)out)[((size_t)s * BB + b) * (DD / 4) + dq] = acc;  // zeros past ns
    }
}

extern "C" void kernel_launch(void* const* d_in, const int* in_sizes, int n_in,
                              void* d_out, int out_size, void* d_ws, size_t ws_size,
                              hipStream_t stream) {
    const float* rep            = (const float*)d_in[0];
    const float* logit          = (const float*)d_in[1];
    const unsigned char* paddng = (const unsigned char*)d_in[2];

    float* out     = (float*)d_out;
    float* out_pad = out + (size_t)TT * BB * DD;     // second output: (B,T) mask

    int* labels = (int*)d_ws;                        // B*T int = 64 KiB

    argmax_kernel<<<(TT * BB) / 16, 1024, 0, stream>>>(logit, labels);
    fused_compress_kernel<<<BB * NCHUNK, 256, 0, stream>>>(labels, paddng, rep, out, out_pad);
}

// Round 4
// 29.636 us; speedup vs baseline: 1.0827x; 1.0077x over previous
//
#include <hip/hip_runtime.h>
#include <cfloat>
#include <climits>

#define TT 1024
#define BB 16
#define DD 512
#define VV 1000
#define CHUNK 16         // output rows (s values) per fused block
#define NCHUNK (TT / CHUNK)

// Kernel 1: one 64-lane wave per (t,b) position computes argmax over V logits.
// 256-thread blocks: fine occupancy granularity (up to 8 blocks/CU).
__global__ void argmax_kernel(const float* __restrict__ logit, int* __restrict__ labels) {
    int gw   = (blockIdx.x * blockDim.x + threadIdx.x) >> 6;   // global wave id = t*B + b
    int lane = threadIdx.x & 63;
    const float4* row = (const float4*)(logit + (size_t)gw * VV);  // 4000B rows, 16B aligned
    float best = -FLT_MAX;
    int   bidx = INT_MAX;
    for (int i = lane; i < VV / 4; i += 64) {           // 250 float4 per row
        float4 v = row[i];
        int base = i * 4;
        if (v.x > best) { best = v.x; bidx = base;     }
        if (v.y > best) { best = v.y; bidx = base + 1; }
        if (v.z > best) { best = v.z; bidx = base + 2; }
        if (v.w > best) { best = v.w; bidx = base + 3; }
    }
    for (int off = 32; off; off >>= 1) {                // first-index tie-break
        float ov = __shfl_xor(best, off);
        int   oi = __shfl_xor(bidx, off);
        if (ov > best || (ov == best && oi < bidx)) { best = ov; bidx = oi; }
    }
    if (lane == 0) {
        int t = gw / BB, b = gw % BB;                   // logit layout is (T,B,V)
        labels[b * TT + t] = bidx;                      // store as (B,T)
    }
}

// Kernel 2: fused segmentation + compression. Block = (batch b, chunk of 16 s).
// Each block redundantly scans batch b's 1024 labels (4KB, L2-hit) into LDS
// seg structures, then gathers its 16 output rows. 256 threads, 4 t's/thread.
__global__ void __launch_bounds__(256) fused_compress_kernel(
        const int* __restrict__ labels,
        const unsigned char* __restrict__ padding,
        const float* __restrict__ rep,
        float* __restrict__ out, float* __restrict__ out_pad) {
    int b = blockIdx.x / NCHUNK;
    int c = blockIdx.x % NCHUNK;
    int tid = threadIdx.x;               // 0..255
    int lane = tid & 63, wid = tid >> 6; // 4 waves
    int t0 = tid * 4;

    __shared__ int   wtot[4];
    __shared__ int   cnt_s[TT];
    __shared__ int   start_s[TT];
    __shared__ float w_s[TT];

    // --- change flags for 4 consecutive t ---
    int4 lab4 = *(const int4*)(labels + b * TT + t0);
    int prev  = (t0 > 0) ? labels[b * TT + t0 - 1] : -1;   // raw previous label
    uchar4 p4 = *(const uchar4*)(padding + b * TT + t0);
    int v0 = !p4.x, v1 = !p4.y, v2 = !p4.z, v3 = !p4.w;
    int c0 = v0 && (lab4.x != prev);
    int c1 = v1 && (lab4.y != lab4.x);
    int c2 = v2 && (lab4.z != lab4.y);
    int c3 = v3 && (lab4.w != lab4.z);
    int l0 = c0, l1 = l0 + c1, l2 = l1 + c2, l3 = l2 + c3;  // local inclusive

    // --- wave inclusive scan of per-thread totals ---
    int x = l3;
    for (int off = 1; off < 64; off <<= 1) {
        int y = __shfl_up(x, off);
        if (lane >= off) x += y;
    }
    if (lane == 63) wtot[wid] = x;
    cnt_s[t0] = 0; cnt_s[t0 + 1] = 0; cnt_s[t0 + 2] = 0; cnt_s[t0 + 3] = 0;
    __syncthreads();
    int woff = 0;
    #pragma unroll
    for (int i = 0; i < 4; ++i) if (i < wid) woff += wtot[i];
    int ns   = wtot[0] + wtot[1] + wtot[2] + wtot[3];  // segments in batch b
    int excl = woff + x - l3;                          // exclusive prefix for t0

    int s0 = excl + l0 - 1, s1 = excl + l1 - 1, s2 = excl + l2 - 1, s3 = excl + l3 - 1;
    if (c0) start_s[s0] = t0;
    if (c1) start_s[s1] = t0 + 1;
    if (c2) start_s[s2] = t0 + 2;
    if (c3) start_s[s3] = t0 + 3;
    if (v0 && s0 >= 0) atomicAdd(&cnt_s[s0], 1);
    if (v1 && s1 >= 0) atomicAdd(&cnt_s[s1], 1);
    if (v2 && s2 >= 0) atomicAdd(&cnt_s[s2], 1);
    if (v3 && s3 >= 0) atomicAdd(&cnt_s[s3], 1);
    __syncthreads();
    w_s[t0]     = (v0 && s0 >= 0) ? (1.0f / (float)cnt_s[s0]) : 0.0f;
    w_s[t0 + 1] = (v1 && s1 >= 0) ? (1.0f / (float)cnt_s[s1]) : 0.0f;
    w_s[t0 + 2] = (v2 && s2 >= 0) ? (1.0f / (float)cnt_s[s2]) : 0.0f;
    w_s[t0 + 3] = (v3 && s3 >= 0) ? (1.0f / (float)cnt_s[s3]) : 0.0f;

    if (c == 0) {   // one chunk per batch emits the new padding mask
        float4 pm;
        pm.x = (t0     >= ns) ? 1.0f : 0.0f;
        pm.y = (t0 + 1 >= ns) ? 1.0f : 0.0f;
        pm.z = (t0 + 2 >= ns) ? 1.0f : 0.0f;
        pm.w = (t0 + 3 >= ns) ? 1.0f : 0.0f;
        *(float4*)(out_pad + b * TT + t0) = pm;
    }
    __syncthreads();

    // --- compress 16 rows: 2 in parallel (128 threads each), 8 iterations ---
    int sub = tid >> 7;                   // row slot 0/1
    int dq  = tid & 127;                  // float4 index within D=512
    #pragma unroll
    for (int r = sub; r < CHUNK; r += 2) {
        int s = c * CHUNK + r;
        float4 acc = make_float4(0.f, 0.f, 0.f, 0.f);
        if (s < ns) {
            int start = start_s[s];
            int end   = (s + 1 < ns) ? start_s[s + 1] : TT;
            for (int t = start; t < end; ++t) {
                float ww = w_s[t];
                if (ww != 0.0f) {
                    float4 rv = ((const float4*)rep)[((size_t)t * BB + b) * (DD / 4) + dq];
                    acc.x += ww * rv.x; acc.y += ww * rv.y;
                    acc.z += ww * rv.z; acc.w += ww * rv.w;
                }
            }
        }
        ((float4*)out)[((size_t)s * BB + b) * (DD / 4) + dq] = acc;  // zeros past ns
    }
}

extern "C" void kernel_launch(void* const* d_in, const int* in_sizes, int n_in,
                              void* d_out, int out_size, void* d_ws, size_t ws_size,
                              hipStream_t stream) {
    const float* rep            = (const float*)d_in[0];
    const float* logit          = (const float*)d_in[1];
    const unsigned char* paddng = (const unsigned char*)d_in[2];

    float* out     = (float*)d_out;
    float* out_pad = out + (size_t)TT * BB * DD;     // second output: (B,T) mask

    int* labels = (int*)d_ws;                        // B*T int = 64 KiB

    argmax_kernel<<<(TT * BB) / 4, 256, 0, stream>>>(logit, labels);
    fused_compress_kernel<<<BB * NCHUNK, 256, 0, stream>>>(labels, paddng, rep, out, out_pad);
}

// Round 5
// 28.966 us; speedup vs baseline: 1.1078x; 1.0231x over previous
//
#include <hip/hip_runtime.h>
#include <cfloat>
#include <climits>

#define TT 1024
#define BB 16
#define DD 512
#define VV 1000
#define CHUNK 16         // output rows (s values) per fused block
#define NCHUNK (TT / CHUNK)
#define KROWS (CHUNK / 2)  // rows per 128-thread slot

// Kernel 1: one 64-lane wave per (t,b) position computes argmax over V logits.
__global__ void argmax_kernel(const float* __restrict__ logit, int* __restrict__ labels) {
    int gw   = (blockIdx.x * blockDim.x + threadIdx.x) >> 6;   // global wave id = t*B + b
    int lane = threadIdx.x & 63;
    const float4* row = (const float4*)(logit + (size_t)gw * VV);  // 4000B rows, 16B aligned
    float best = -FLT_MAX;
    int   bidx = INT_MAX;
    for (int i = lane; i < VV / 4; i += 64) {           // 250 float4 per row
        float4 v = row[i];
        int base = i * 4;
        if (v.x > best) { best = v.x; bidx = base;     }
        if (v.y > best) { best = v.y; bidx = base + 1; }
        if (v.z > best) { best = v.z; bidx = base + 2; }
        if (v.w > best) { best = v.w; bidx = base + 3; }
    }
    for (int off = 32; off; off >>= 1) {                // first-index tie-break
        float ov = __shfl_xor(best, off);
        int   oi = __shfl_xor(bidx, off);
        if (ov > best || (ov == best && oi < bidx)) { best = ov; bidx = oi; }
    }
    if (lane == 0) {
        int t = gw / BB, b = gw % BB;                   // logit layout is (T,B,V)
        labels[b * TT + t] = bidx;                      // store as (B,T)
    }
}

// Kernel 2: fused segmentation + compression. Block = (batch b, chunk of 16 s).
// Scan prologue builds per-batch segment structures in LDS; compress phase
// prefetches the first timestep of all 8 rows per 128-thread slot (8 loads in
// flight per wave) and falls back to a rare slow path for len>1 segments.
__global__ void __launch_bounds__(256) fused_compress_kernel(
        const int* __restrict__ labels,
        const unsigned char* __restrict__ padding,
        const float* __restrict__ rep,
        float* __restrict__ out, float* __restrict__ out_pad) {
    int b = blockIdx.x / NCHUNK;
    int c = blockIdx.x % NCHUNK;
    int tid = threadIdx.x;               // 0..255
    int lane = tid & 63, wid = tid >> 6; // 4 waves
    int t0 = tid * 4;

    __shared__ int   wtot[4];
    __shared__ int   cnt_s[TT];
    __shared__ int   start_s[TT];
    __shared__ float w_s[TT];

    // --- change flags for 4 consecutive t ---
    int4 lab4 = *(const int4*)(labels + b * TT + t0);
    int prev  = (t0 > 0) ? labels[b * TT + t0 - 1] : -1;   // raw previous label
    uchar4 p4 = *(const uchar4*)(padding + b * TT + t0);
    int v0 = !p4.x, v1 = !p4.y, v2 = !p4.z, v3 = !p4.w;
    int c0 = v0 && (lab4.x != prev);
    int c1 = v1 && (lab4.y != lab4.x);
    int c2 = v2 && (lab4.z != lab4.y);
    int c3 = v3 && (lab4.w != lab4.z);
    int l0 = c0, l1 = l0 + c1, l2 = l1 + c2, l3 = l2 + c3;  // local inclusive

    // --- wave inclusive scan of per-thread totals ---
    int x = l3;
    for (int off = 1; off < 64; off <<= 1) {
        int y = __shfl_up(x, off);
        if (lane >= off) x += y;
    }
    if (lane == 63) wtot[wid] = x;
    cnt_s[t0] = 0; cnt_s[t0 + 1] = 0; cnt_s[t0 + 2] = 0; cnt_s[t0 + 3] = 0;
    __syncthreads();
    int woff = 0;
    #pragma unroll
    for (int i = 0; i < 4; ++i) if (i < wid) woff += wtot[i];
    int ns   = wtot[0] + wtot[1] + wtot[2] + wtot[3];  // segments in batch b
    int excl = woff + x - l3;                          // exclusive prefix for t0

    int s0 = excl + l0 - 1, s1 = excl + l1 - 1, s2 = excl + l2 - 1, s3 = excl + l3 - 1;
    if (c0) start_s[s0] = t0;
    if (c1) start_s[s1] = t0 + 1;
    if (c2) start_s[s2] = t0 + 2;
    if (c3) start_s[s3] = t0 + 3;
    if (v0 && s0 >= 0) atomicAdd(&cnt_s[s0], 1);
    if (v1 && s1 >= 0) atomicAdd(&cnt_s[s1], 1);
    if (v2 && s2 >= 0) atomicAdd(&cnt_s[s2], 1);
    if (v3 && s3 >= 0) atomicAdd(&cnt_s[s3], 1);
    __syncthreads();
    w_s[t0]     = (v0 && s0 >= 0) ? (1.0f / (float)cnt_s[s0]) : 0.0f;
    w_s[t0 + 1] = (v1 && s1 >= 0) ? (1.0f / (float)cnt_s[s1]) : 0.0f;
    w_s[t0 + 2] = (v2 && s2 >= 0) ? (1.0f / (float)cnt_s[s2]) : 0.0f;
    w_s[t0 + 3] = (v3 && s3 >= 0) ? (1.0f / (float)cnt_s[s3]) : 0.0f;

    if (c == 0) {   // one chunk per batch emits the new padding mask
        float4 pm;
        pm.x = (t0     >= ns) ? 1.0f : 0.0f;
        pm.y = (t0 + 1 >= ns) ? 1.0f : 0.0f;
        pm.z = (t0 + 2 >= ns) ? 1.0f : 0.0f;
        pm.w = (t0 + 3 >= ns) ? 1.0f : 0.0f;
        *(float4*)(out_pad + b * TT + t0) = pm;
    }
    __syncthreads();

    // --- compress 16 rows: 2 slots of 128 threads, 8 rows each, ILP=8 ---
    int sub = tid >> 7;                   // row slot 0/1
    int dq  = tid & 127;                  // float4 index within D=512
    const float4* rep4 = (const float4*)rep;

    int    st[KROWS];
    int    en[KROWS];
    float4 rv[KROWS];
    bool   ok[KROWS];
    #pragma unroll
    for (int k = 0; k < KROWS; ++k) {     // issue 8 independent first-t loads
        int s = c * CHUNK + sub + 2 * k;
        ok[k] = (s < ns);
        int t1 = ok[k] ? start_s[s] : 0;
        st[k] = t1;
        en[k] = ok[k] ? ((s + 1 < ns) ? start_s[s + 1] : TT) : 0;
        if (ok[k]) rv[k] = rep4[((size_t)t1 * BB + b) * (DD / 4) + dq];
    }
    #pragma unroll
    for (int k = 0; k < KROWS; ++k) {
        int s = c * CHUNK + sub + 2 * k;
        float4 acc = make_float4(0.f, 0.f, 0.f, 0.f);
        if (ok[k]) {
            float ww = w_s[st[k]];        // segment start is always valid (w>0)
            acc.x = ww * rv[k].x; acc.y = ww * rv[k].y;
            acc.z = ww * rv[k].z; acc.w = ww * rv[k].w;
            // rare slow path: segments longer than one timestep
            for (int t = st[k] + 1; t < en[k]; ++t) {
                float w2 = w_s[t];
                if (w2 != 0.0f) {         // skips invalid (padded) timesteps
                    float4 rv2 = rep4[((size_t)t * BB + b) * (DD / 4) + dq];
                    acc.x += w2 * rv2.x; acc.y += w2 * rv2.y;
                    acc.z += w2 * rv2.z; acc.w += w2 * rv2.w;
                }
            }
        }
        ((float4*)out)[((size_t)s * BB + b) * (DD / 4) + dq] = acc;  // zeros past ns
    }
}

extern "C" void kernel_launch(void* const* d_in, const int* in_sizes, int n_in,
                              void* d_out, int out_size, void* d_ws, size_t ws_size,
                              hipStream_t stream) {
    const float* rep            = (const float*)d_in[0];
    const float* logit          = (const float*)d_in[1];
    const unsigned char* paddng = (const unsigned char*)d_in[2];

    float* out     = (float*)d_out;
    float* out_pad = out + (size_t)TT * BB * DD;     // second output: (B,T) mask

    int* labels = (int*)d_ws;                        // B*T int = 64 KiB

    argmax_kernel<<<(TT * BB) / 4, 256, 0, stream>>>(logit, labels);
    fused_compress_kernel<<<BB * NCHUNK, 256, 0, stream>>>(labels, paddng, rep, out, out_pad);
}